// Round 10
// baseline (244.290 us; speedup 1.0000x reference)
//
#include <hip/hip_runtime.h>
#include <hip/hip_cooperative_groups.h>

namespace cg = cooperative_groups;

#define CDIM 2048
#define BATCH 32
#define K2 4096
#define BN 64
#define BK 128
#define KT (K2 / BK)    // 32
#define NT (CDIM / BN)  // 32
#define GRID 512

typedef float f32x4 __attribute__((ext_vector_type(4)));

// ======================= standalone (fallback) kernels =======================

__global__ __launch_bounds__(256) void gemm_partial_k(
    const float* __restrict__ x1, const float* __restrict__ x2,
    const float* __restrict__ W, float* __restrict__ partial)
{
    __shared__ float lds[BN * BK + BATCH * BK];
    float* Wt = lds;
    float* Xs = lds + BN * BK;

    const int nt = blockIdx.x, kt = blockIdx.y;
    const int i0 = nt * BN, k0 = kt * BK;
    const int t = threadIdx.x;
    const int lane = t & 63, ks = t >> 6;
    const int cg8 = lane & 7, bg = lane >> 3;

    const float* xsrc = (k0 < CDIM) ? x1 : x2;
    const int kk0 = k0 & (CDIM - 1);

    #pragma unroll
    for (int r = 0; r < 8; ++r) {
        int f = t + 256 * r;
        int row = f >> 5, kc = f & 31;
        float4 v = *reinterpret_cast<const float4*>(W + (size_t)(i0 + row) * K2 + k0 + kc * 4);
        int sc = kc ^ ((row >> 3) & 7);
        *reinterpret_cast<float4*>(&Wt[row * BK + sc * 4]) = v;
    }
    #pragma unroll
    for (int r = 0; r < 4; ++r) {
        int f = t + 256 * r;
        int row = f >> 5, kc = f & 31;
        float4 v = *reinterpret_cast<const float4*>(xsrc + row * CDIM + kk0 + kc * 4);
        int sc = kc ^ ((row >> 2) & 7);
        *reinterpret_cast<float4*>(&Xs[row * BK + sc * 4]) = v;
    }
    __syncthreads();

    float acc[4][8] = {};
    #pragma unroll 2
    for (int s = 0; s < 8; ++s) {
        const int kc = ks * 8 + s;
        f32x4 xv[4], wv[8];
        #pragma unroll
        for (int bb = 0; bb < 4; ++bb)
            xv[bb] = *reinterpret_cast<const f32x4*>(&Xs[(4 * bg + bb) * BK + (kc ^ bg) * 4]);
        #pragma unroll
        for (int cc = 0; cc < 8; ++cc)
            wv[cc] = *reinterpret_cast<const f32x4*>(&Wt[(8 * cg8 + cc) * BK + (kc ^ cg8) * 4]);
        #pragma unroll
        for (int bb = 0; bb < 4; ++bb)
            #pragma unroll
            for (int cc = 0; cc < 8; ++cc)
                #pragma unroll
                for (int w = 0; w < 4; ++w)
                    acc[bb][cc] = fmaf(xv[bb][w], wv[cc][w], acc[bb][cc]);
    }

    __syncthreads();
    float* accS = lds;
    #pragma unroll
    for (int bb = 0; bb < 4; ++bb)
        #pragma unroll
        for (int cc = 0; cc < 8; ++cc)
            accS[(ks * 64 + lane) * 33 + bb * 8 + cc] = acc[bb][cc];
    __syncthreads();

    {
        const int l0 = t >> 2, q = t & 3;
        float s0[8];
        #pragma unroll
        for (int j = 0; j < 8; ++j) {
            float s = 0.f;
            #pragma unroll
            for (int k = 0; k < 4; ++k)
                s += accS[(k * 64 + l0) * 33 + q * 8 + j];
            s0[j] = s;
        }
        const int b_row = 4 * (l0 >> 3) + q;
        const int icol  = 8 * (l0 & 7);
        float* dst = partial + (size_t)kt * (BATCH * CDIM) + b_row * CDIM + i0 + icol;
        *reinterpret_cast<float4*>(dst)     = make_float4(s0[0], s0[1], s0[2], s0[3]);
        *reinterpret_cast<float4*>(dst + 4) = make_float4(s0[4], s0[5], s0[6], s0[7]);
    }
}

__global__ __launch_bounds__(256) void reduce_x_k(
    const float* __restrict__ partial, const float* __restrict__ bias,
    float* __restrict__ x)
{
    int idx = blockIdx.x * 256 + threadIdx.x;
    float s = 0.f;
    #pragma unroll
    for (int kt = 0; kt < KT; ++kt) s += partial[(size_t)kt * (BATCH * CDIM) + idx];
    x[idx] = s + bias[idx & (CDIM - 1)];
}

__global__ __launch_bounds__(256) void attn_k(
    const float* __restrict__ x, const float* __restrict__ x1,
    const float* __restrict__ x2, float* __restrict__ out1,
    float* __restrict__ out2, float* __restrict__ att)
{
    __shared__ float xs[CDIM];
    __shared__ float xs1[CDIM];
    __shared__ float xs2[CDIM];
    __shared__ float wred[8];
    const int b = blockIdx.x >> 5, rg = blockIdx.x & 31;
    const int t = threadIdx.x;
    const int lane = t & 63, wv = t >> 6;
    const float* xb  = x  + b * CDIM;
    const float* x1b = x1 + b * CDIM;
    const float* x2b = x2 + b * CDIM;

    #pragma unroll
    for (int r = 0; r < 2; ++r) {
        int f = (t + 256 * r) * 4;
        *reinterpret_cast<float4*>(&xs[f])  = *reinterpret_cast<const float4*>(xb  + f);
        *reinterpret_cast<float4*>(&xs1[f]) = *reinterpret_cast<const float4*>(x1b + f);
        *reinterpret_cast<float4*>(&xs2[f]) = *reinterpret_cast<const float4*>(x2b + f);
    }
    __syncthreads();

    float mn = 1e30f, mx = -1e30f;
    for (int f = t; f < CDIM; f += 256) {
        float v = xs[f];
        mn = fminf(mn, v); mx = fmaxf(mx, v);
    }
    #pragma unroll
    for (int off = 32; off > 0; off >>= 1) {
        mn = fminf(mn, __shfl_xor(mn, off));
        mx = fmaxf(mx, __shfl_xor(mx, off));
    }
    if (lane == 0) { wred[wv] = mn; wred[4 + wv] = mx; }
    __syncthreads();
    mn = fminf(fminf(wred[0], wred[1]), fminf(wred[2], wred[3]));
    mx = fmaxf(fmaxf(wred[4], wred[5]), fmaxf(wred[6], wred[7]));

    for (int r = 0; r < 16; ++r) {
        const int i = rg * 64 + wv * 16 + r;
        const float xi = xs[i];
        const float li = (xi >= 0.f) ? xi * mn : xi * mx;
        const float nxi = -xi;
        float sum = 0.f, d1 = 0.f, d2 = 0.f;
        #pragma unroll
        for (int g = 0; g < 8; ++g) {
            const int o = g * 256 + lane * 4;
            f32x4 xv = *reinterpret_cast<const f32x4*>(&xs[o]);
            f32x4 v1 = *reinterpret_cast<const f32x4*>(&xs1[o]);
            f32x4 v2 = *reinterpret_cast<const f32x4*>(&xs2[o]);
            #pragma unroll
            for (int c = 0; c < 4; ++c) {
                float ev = __expf(fmaf(nxi, xv[c], li));
                sum += ev;
                d1 = fmaf(ev, v1[c], d1);
                d2 = fmaf(ev, v2[c], d2);
            }
        }
        #pragma unroll
        for (int off = 32; off > 0; off >>= 1) {
            sum += __shfl_xor(sum, off);
            d1  += __shfl_xor(d1, off);
            d2  += __shfl_xor(d2, off);
        }
        const float inv = 1.f / sum;
        if (lane == 0) {
            out1[b * CDIM + i] = fmaf(d1, inv, xs1[i]);
            out2[b * CDIM + i] = fmaf(d2, inv, xs2[i]);
        }
        float* arow = att + (size_t)(b * CDIM + i) * CDIM;
        #pragma unroll
        for (int g = 0; g < 8; ++g) {
            const int o = g * 256 + lane * 4;
            f32x4 xv = *reinterpret_cast<const f32x4*>(&xs[o]);
            f32x4 v;
            #pragma unroll
            for (int c = 0; c < 4; ++c)
                v[c] = __expf(fmaf(nxi, xv[c], li)) * inv;
            *reinterpret_cast<f32x4*>(arow + o) = v;
        }
    }
}

// ======================= fused cooperative kernel =======================
// Bit-identical math to the three kernels above; phases separated by
// grid.sync(). 512 blocks: 2 GEMM tiles, 128 reduce elems, 2 attn units.
__global__ __launch_bounds__(256, 2) void fused_k(
    const float* __restrict__ x1, const float* __restrict__ x2,
    const float* __restrict__ W, const float* __restrict__ bias,
    float* __restrict__ out1, float* __restrict__ out2,
    float* __restrict__ att, float* __restrict__ partial,
    float* __restrict__ xrow)
{
    __shared__ float lds[BN * BK + BATCH * BK]; // 12288 floats = 48 KB
    const int t = threadIdx.x;
    const int lane = t & 63, wv = t >> 6;
    cg::grid_group grid = cg::this_grid();

    // phase 1: GEMM partials, 2 tiles/block
    {
        float* Wt = lds;
        float* Xs = lds + BN * BK;
        const int ks = wv;
        const int cg8 = lane & 7, bg = lane >> 3;

        #pragma unroll
        for (int tile = 0; tile < 2; ++tile) {
            const int tau = blockIdx.x + tile * GRID;
            const int nt = tau & 31, kt = tau >> 5;
            const int i0 = nt * BN, k0 = kt * BK;
            const float* xsrc = (k0 < CDIM) ? x1 : x2;
            const int kk0 = k0 & (CDIM - 1);

            #pragma unroll
            for (int r = 0; r < 8; ++r) {
                int f = t + 256 * r;
                int row = f >> 5, kc = f & 31;
                float4 v = *reinterpret_cast<const float4*>(
                    W + (size_t)(i0 + row) * K2 + k0 + kc * 4);
                int sc = kc ^ ((row >> 3) & 7);
                *reinterpret_cast<float4*>(&Wt[row * BK + sc * 4]) = v;
            }
            #pragma unroll
            for (int r = 0; r < 4; ++r) {
                int f = t + 256 * r;
                int row = f >> 5, kc = f & 31;
                float4 v = *reinterpret_cast<const float4*>(
                    xsrc + row * CDIM + kk0 + kc * 4);
                int sc = kc ^ ((row >> 2) & 7);
                *reinterpret_cast<float4*>(&Xs[row * BK + sc * 4]) = v;
            }
            __syncthreads();

            float acc[4][8] = {};
            #pragma unroll 2
            for (int s = 0; s < 8; ++s) {
                const int kc = ks * 8 + s;
                f32x4 xv[4], wvv[8];
                #pragma unroll
                for (int bb = 0; bb < 4; ++bb)
                    xv[bb] = *reinterpret_cast<const f32x4*>(
                        &Xs[(4 * bg + bb) * BK + (kc ^ bg) * 4]);
                #pragma unroll
                for (int cc = 0; cc < 8; ++cc)
                    wvv[cc] = *reinterpret_cast<const f32x4*>(
                        &Wt[(8 * cg8 + cc) * BK + (kc ^ cg8) * 4]);
                #pragma unroll
                for (int bb = 0; bb < 4; ++bb)
                    #pragma unroll
                    for (int cc = 0; cc < 8; ++cc)
                        #pragma unroll
                        for (int w = 0; w < 4; ++w)
                            acc[bb][cc] = fmaf(xv[bb][w], wvv[cc][w], acc[bb][cc]);
            }

            __syncthreads();
            float* accS = lds;
            #pragma unroll
            for (int bb = 0; bb < 4; ++bb)
                #pragma unroll
                for (int cc = 0; cc < 8; ++cc)
                    accS[(ks * 64 + lane) * 33 + bb * 8 + cc] = acc[bb][cc];
            __syncthreads();

            {
                const int l0 = t >> 2, q = t & 3;
                float s0[8];
                #pragma unroll
                for (int j = 0; j < 8; ++j) {
                    float s = 0.f;
                    #pragma unroll
                    for (int k = 0; k < 4; ++k)
                        s += accS[(k * 64 + l0) * 33 + q * 8 + j];
                    s0[j] = s;
                }
                const int b_row = 4 * (l0 >> 3) + q;
                const int icol  = 8 * (l0 & 7);
                float* dst = partial + (size_t)kt * (BATCH * CDIM)
                             + b_row * CDIM + i0 + icol;
                *reinterpret_cast<float4*>(dst) =
                    make_float4(s0[0], s0[1], s0[2], s0[3]);
                *reinterpret_cast<float4*>(dst + 4) =
                    make_float4(s0[4], s0[5], s0[6], s0[7]);
            }
            __syncthreads();
        }
    }

    grid.sync();

    // phase 2: reduce partials -> xrow (128 elems/block)
    if (t < 128) {
        const int idx = blockIdx.x * 128 + t;
        float s = 0.f;
        #pragma unroll
        for (int kt = 0; kt < KT; ++kt)
            s += partial[(size_t)kt * (BATCH * CDIM) + idx];
        xrow[idx] = s + bias[idx & (CDIM - 1)];
    }

    grid.sync();

    // phase 3: attention, 2 units/block
    {
        float* xs   = lds;
        float* xs1  = lds + CDIM;
        float* xs2  = lds + 2 * CDIM;
        float* wred = lds + 3 * CDIM;

        #pragma unroll
        for (int u = 0; u < 2; ++u) {
            const int unit = blockIdx.x * 2 + u;
            const int b = unit >> 5, rg = unit & 31;
            const float* xb  = xrow + b * CDIM;
            const float* x1b = x1 + b * CDIM;
            const float* x2b = x2 + b * CDIM;

            __syncthreads();
            #pragma unroll
            for (int r = 0; r < 2; ++r) {
                int f = (t + 256 * r) * 4;
                *reinterpret_cast<float4*>(&xs[f])  = *reinterpret_cast<const float4*>(xb  + f);
                *reinterpret_cast<float4*>(&xs1[f]) = *reinterpret_cast<const float4*>(x1b + f);
                *reinterpret_cast<float4*>(&xs2[f]) = *reinterpret_cast<const float4*>(x2b + f);
            }
            __syncthreads();

            float mn = 1e30f, mx = -1e30f;
            for (int f = t; f < CDIM; f += 256) {
                float v = xs[f];
                mn = fminf(mn, v); mx = fmaxf(mx, v);
            }
            #pragma unroll
            for (int off = 32; off > 0; off >>= 1) {
                mn = fminf(mn, __shfl_xor(mn, off));
                mx = fmaxf(mx, __shfl_xor(mx, off));
            }
            if (lane == 0) { wred[wv] = mn; wred[4 + wv] = mx; }
            __syncthreads();
            mn = fminf(fminf(wred[0], wred[1]), fminf(wred[2], wred[3]));
            mx = fmaxf(fmaxf(wred[4], wred[5]), fmaxf(wred[6], wred[7]));

            for (int r = 0; r < 16; ++r) {
                const int i = rg * 64 + wv * 16 + r;
                const float xi = xs[i];
                const float li = (xi >= 0.f) ? xi * mn : xi * mx;
                const float nxi = -xi;
                float sum = 0.f, d1 = 0.f, d2 = 0.f;
                #pragma unroll
                for (int g = 0; g < 8; ++g) {
                    const int o = g * 256 + lane * 4;
                    f32x4 xv = *reinterpret_cast<const f32x4*>(&xs[o]);
                    f32x4 v1 = *reinterpret_cast<const f32x4*>(&xs1[o]);
                    f32x4 v2 = *reinterpret_cast<const f32x4*>(&xs2[o]);
                    #pragma unroll
                    for (int c = 0; c < 4; ++c) {
                        float ev = __expf(fmaf(nxi, xv[c], li));
                        sum += ev;
                        d1 = fmaf(ev, v1[c], d1);
                        d2 = fmaf(ev, v2[c], d2);
                    }
                }
                #pragma unroll
                for (int off = 32; off > 0; off >>= 1) {
                    sum += __shfl_xor(sum, off);
                    d1  += __shfl_xor(d1, off);
                    d2  += __shfl_xor(d2, off);
                }
                const float inv = 1.f / sum;
                if (lane == 0) {
                    out1[b * CDIM + i] = fmaf(d1, inv, xs1[i]);
                    out2[b * CDIM + i] = fmaf(d2, inv, xs2[i]);
                }
                float* arow = att + (size_t)(b * CDIM + i) * CDIM;
                #pragma unroll
                for (int g = 0; g < 8; ++g) {
                    const int o = g * 256 + lane * 4;
                    f32x4 xv = *reinterpret_cast<const f32x4*>(&xs[o]);
                    f32x4 v;
                    #pragma unroll
                    for (int c = 0; c < 4; ++c)
                        v[c] = __expf(fmaf(nxi, xv[c], li)) * inv;
                    *reinterpret_cast<f32x4*>(arow + o) = v;
                }
            }
        }
    }
}

extern "C" void kernel_launch(void* const* d_in, const int* in_sizes, int n_in,
                              void* d_out, int out_size, void* d_ws, size_t ws_size,
                              hipStream_t stream) {
    const float* x1   = (const float*)d_in[0];
    const float* x2   = (const float*)d_in[1];
    const float* W    = (const float*)d_in[2];
    const float* bias = (const float*)d_in[3];
    float* out  = (float*)d_out;
    float* out1 = out;
    float* out2 = out + BATCH * CDIM;
    float* att  = out + 2 * BATCH * CDIM;
    float* xrow = (float*)d_ws;

    // GEMM partials live in the tail of the attention region; fully consumed
    // (phase 2 / reduce_x_k) before the attention phase overwrites them.
    float* partial = out + ((size_t)out_size - (size_t)KT * BATCH * CDIM);

    void* args[] = {(void*)&x1, (void*)&x2, (void*)&W, (void*)&bias,
                    (void*)&out1, (void*)&out2, (void*)&att,
                    (void*)&partial, (void*)&xrow};
    hipError_t err = hipLaunchCooperativeKernel((const void*)fused_k,
                                                dim3(GRID), dim3(256),
                                                args, 0, stream);
    if (err != hipSuccess) {
        (void)hipGetLastError(); // clear sticky error; fall back to 3-kernel path
        gemm_partial_k<<<dim3(NT, KT), dim3(256), 0, stream>>>(x1, x2, W, partial);
        reduce_x_k<<<(BATCH * CDIM) / 256, 256, 0, stream>>>(partial, bias, xrow);
        attn_k<<<BATCH * (CDIM / 64), 256, 0, stream>>>(xrow, x1, x2, out1, out2, att);
    }
}

// Round 11
// 157.699 us; speedup vs baseline: 1.5491x; 1.5491x over previous
//
#include <hip/hip_runtime.h>

#define CDIM 2048
#define BATCH 32
#define K2 4096
#define BN 64
#define BK 128
#define KT (K2 / BK)    // 32
#define NT (CDIM / BN)  // 32

typedef float f32x4 __attribute__((ext_vector_type(4)));

// ---- GEMM partial (R7): partial[kt] = xcat[:, k0:k0+BK] @ W[:, k0:k0+BK]^T ----
__global__ __launch_bounds__(256) void gemm_partial_k(
    const float* __restrict__ x1, const float* __restrict__ x2,
    const float* __restrict__ W, float* __restrict__ partial)
{
    __shared__ float lds[BN * BK + BATCH * BK];
    float* Wt = lds;
    float* Xs = lds + BN * BK;

    const int nt = blockIdx.x, kt = blockIdx.y;
    const int i0 = nt * BN, k0 = kt * BK;
    const int t = threadIdx.x;
    const int lane = t & 63, ks = t >> 6;
    const int cg8 = lane & 7, bg = lane >> 3;

    const float* xsrc = (k0 < CDIM) ? x1 : x2;
    const int kk0 = k0 & (CDIM - 1);

    #pragma unroll
    for (int r = 0; r < 8; ++r) {
        int f = t + 256 * r;
        int row = f >> 5, kc = f & 31;
        float4 v = *reinterpret_cast<const float4*>(W + (size_t)(i0 + row) * K2 + k0 + kc * 4);
        int sc = kc ^ ((row >> 3) & 7);
        *reinterpret_cast<float4*>(&Wt[row * BK + sc * 4]) = v;
    }
    #pragma unroll
    for (int r = 0; r < 4; ++r) {
        int f = t + 256 * r;
        int row = f >> 5, kc = f & 31;
        float4 v = *reinterpret_cast<const float4*>(xsrc + row * CDIM + kk0 + kc * 4);
        int sc = kc ^ ((row >> 2) & 7);
        *reinterpret_cast<float4*>(&Xs[row * BK + sc * 4]) = v;
    }
    __syncthreads();

    float acc[4][8] = {};
    #pragma unroll 2
    for (int s = 0; s < 8; ++s) {
        const int kc = ks * 8 + s;
        f32x4 xv[4], wv[8];
        #pragma unroll
        for (int bb = 0; bb < 4; ++bb)
            xv[bb] = *reinterpret_cast<const f32x4*>(&Xs[(4 * bg + bb) * BK + (kc ^ bg) * 4]);
        #pragma unroll
        for (int cc = 0; cc < 8; ++cc)
            wv[cc] = *reinterpret_cast<const f32x4*>(&Wt[(8 * cg8 + cc) * BK + (kc ^ cg8) * 4]);
        #pragma unroll
        for (int bb = 0; bb < 4; ++bb)
            #pragma unroll
            for (int cc = 0; cc < 8; ++cc)
                #pragma unroll
                for (int w = 0; w < 4; ++w)
                    acc[bb][cc] = fmaf(xv[bb][w], wv[cc][w], acc[bb][cc]);
    }

    __syncthreads();
    float* accS = lds;
    #pragma unroll
    for (int bb = 0; bb < 4; ++bb)
        #pragma unroll
        for (int cc = 0; cc < 8; ++cc)
            accS[(ks * 64 + lane) * 33 + bb * 8 + cc] = acc[bb][cc];
    __syncthreads();

    {
        const int l0 = t >> 2, q = t & 3;
        float s0[8];
        #pragma unroll
        for (int j = 0; j < 8; ++j) {
            float s = 0.f;
            #pragma unroll
            for (int k = 0; k < 4; ++k)
                s += accS[(k * 64 + l0) * 33 + q * 8 + j];
            s0[j] = s;
        }
        const int b_row = 4 * (l0 >> 3) + q;
        const int icol  = 8 * (l0 & 7);
        float* dst = partial + (size_t)kt * (BATCH * CDIM) + b_row * CDIM + i0 + icol;
        *reinterpret_cast<float4*>(dst)     = make_float4(s0[0], s0[1], s0[2], s0[3]);
        *reinterpret_cast<float4*>(dst + 4) = make_float4(s0[4], s0[5], s0[6], s0[7]);
    }
}

__global__ __launch_bounds__(256) void reduce_x_k(
    const float* __restrict__ partial, const float* __restrict__ bias,
    float* __restrict__ x)
{
    int idx = blockIdx.x * 256 + threadIdx.x;
    float s = 0.f;
    #pragma unroll
    for (int kt = 0; kt < KT; ++kt) s += partial[(size_t)kt * (BATCH * CDIM) + idx];
    x[idx] = s + bias[idx & (CDIM - 1)];
}

// ---- A: per-row sums (pass 1) -> out1/out2 + li/inv stash ----
__global__ __launch_bounds__(256) void attn_sums_k(
    const float* __restrict__ x, const float* __restrict__ x1,
    const float* __restrict__ x2, float* __restrict__ out1,
    float* __restrict__ out2, float* __restrict__ liS,
    float* __restrict__ invS)
{
    __shared__ float xs[CDIM];
    __shared__ float xs1[CDIM];
    __shared__ float xs2[CDIM];
    __shared__ float wred[8];
    const int b = blockIdx.x >> 5, rg = blockIdx.x & 31;
    const int t = threadIdx.x;
    const int lane = t & 63, wv = t >> 6;
    const float* xb  = x  + b * CDIM;
    const float* x1b = x1 + b * CDIM;
    const float* x2b = x2 + b * CDIM;

    #pragma unroll
    for (int r = 0; r < 2; ++r) {
        int f = (t + 256 * r) * 4;
        *reinterpret_cast<float4*>(&xs[f])  = *reinterpret_cast<const float4*>(xb  + f);
        *reinterpret_cast<float4*>(&xs1[f]) = *reinterpret_cast<const float4*>(x1b + f);
        *reinterpret_cast<float4*>(&xs2[f]) = *reinterpret_cast<const float4*>(x2b + f);
    }
    __syncthreads();

    float mn = 1e30f, mx = -1e30f;
    for (int f = t; f < CDIM; f += 256) {
        float v = xs[f];
        mn = fminf(mn, v); mx = fmaxf(mx, v);
    }
    #pragma unroll
    for (int off = 32; off > 0; off >>= 1) {
        mn = fminf(mn, __shfl_xor(mn, off));
        mx = fmaxf(mx, __shfl_xor(mx, off));
    }
    if (lane == 0) { wred[wv] = mn; wred[4 + wv] = mx; }
    __syncthreads();
    mn = fminf(fminf(wred[0], wred[1]), fminf(wred[2], wred[3]));
    mx = fmaxf(fmaxf(wred[4], wred[5]), fmaxf(wred[6], wred[7]));

    for (int r = 0; r < 16; ++r) {
        const int i = rg * 64 + wv * 16 + r;
        const float xi = xs[i];
        const float li = (xi >= 0.f) ? xi * mn : xi * mx; // min_j(x_i*x_j), exact
        const float nxi = -xi;
        float sum = 0.f, d1 = 0.f, d2 = 0.f;
        #pragma unroll
        for (int g = 0; g < 8; ++g) {
            const int o = g * 256 + lane * 4;
            f32x4 xv = *reinterpret_cast<const f32x4*>(&xs[o]);
            f32x4 v1 = *reinterpret_cast<const f32x4*>(&xs1[o]);
            f32x4 v2 = *reinterpret_cast<const f32x4*>(&xs2[o]);
            #pragma unroll
            for (int c = 0; c < 4; ++c) {
                float ev = __expf(fmaf(nxi, xv[c], li));
                sum += ev;
                d1 = fmaf(ev, v1[c], d1);
                d2 = fmaf(ev, v2[c], d2);
            }
        }
        #pragma unroll
        for (int off = 32; off > 0; off >>= 1) {
            sum += __shfl_xor(sum, off);
            d1  += __shfl_xor(d1, off);
            d2  += __shfl_xor(d2, off);
        }
        const float inv = 1.f / sum;
        if (lane == 0) {
            out1[b * CDIM + i] = fmaf(d1, inv, xs1[i]);
            out2[b * CDIM + i] = fmaf(d2, inv, xs2[i]);
            liS [b * CDIM + i] = li;
            invS[b * CDIM + i] = inv;
        }
    }
}

// ---- B: pure store sweep — no per-row reduction dependency; stores start
// immediately after an 8 KB stage. ----
__global__ __launch_bounds__(256) void attn_store_k(
    const float* __restrict__ x, const float* __restrict__ liS,
    const float* __restrict__ invS, float* __restrict__ att)
{
    __shared__ float xs[CDIM];
    const int b = blockIdx.x >> 5, rg = blockIdx.x & 31;
    const int t = threadIdx.x;
    const int lane = t & 63, wv = t >> 6;
    const float* xb = x + b * CDIM;

    #pragma unroll
    for (int r = 0; r < 2; ++r) {
        int f = (t + 256 * r) * 4;
        *reinterpret_cast<float4*>(&xs[f]) = *reinterpret_cast<const float4*>(xb + f);
    }
    __syncthreads();

    for (int r = 0; r < 16; ++r) {
        const int i = rg * 64 + wv * 16 + r;
        const float li  = liS [b * CDIM + i];
        const float inv = invS[b * CDIM + i];
        const float nxi = -xs[i];
        float* arow = att + (size_t)(b * CDIM + i) * CDIM;
        #pragma unroll
        for (int g = 0; g < 8; ++g) {
            const int o = g * 256 + lane * 4;
            f32x4 xv = *reinterpret_cast<const f32x4*>(&xs[o]);
            f32x4 v;
            #pragma unroll
            for (int c = 0; c < 4; ++c)
                v[c] = __expf(fmaf(nxi, xv[c], li)) * inv;
            *reinterpret_cast<f32x4*>(arow + o) = v;
        }
    }
}

// ---- fallback attn (R7 interleaved) if ws too small ----
__global__ __launch_bounds__(256) void attn_k(
    const float* __restrict__ x, const float* __restrict__ x1,
    const float* __restrict__ x2, float* __restrict__ out1,
    float* __restrict__ out2, float* __restrict__ att)
{
    __shared__ float xs[CDIM];
    __shared__ float xs1[CDIM];
    __shared__ float xs2[CDIM];
    __shared__ float wred[8];
    const int b = blockIdx.x >> 5, rg = blockIdx.x & 31;
    const int t = threadIdx.x;
    const int lane = t & 63, wv = t >> 6;
    const float* xb  = x  + b * CDIM;
    const float* x1b = x1 + b * CDIM;
    const float* x2b = x2 + b * CDIM;

    #pragma unroll
    for (int r = 0; r < 2; ++r) {
        int f = (t + 256 * r) * 4;
        *reinterpret_cast<float4*>(&xs[f])  = *reinterpret_cast<const float4*>(xb  + f);
        *reinterpret_cast<float4*>(&xs1[f]) = *reinterpret_cast<const float4*>(x1b + f);
        *reinterpret_cast<float4*>(&xs2[f]) = *reinterpret_cast<const float4*>(x2b + f);
    }
    __syncthreads();

    float mn = 1e30f, mx = -1e30f;
    for (int f = t; f < CDIM; f += 256) {
        float v = xs[f];
        mn = fminf(mn, v); mx = fmaxf(mx, v);
    }
    #pragma unroll
    for (int off = 32; off > 0; off >>= 1) {
        mn = fminf(mn, __shfl_xor(mn, off));
        mx = fmaxf(mx, __shfl_xor(mx, off));
    }
    if (lane == 0) { wred[wv] = mn; wred[4 + wv] = mx; }
    __syncthreads();
    mn = fminf(fminf(wred[0], wred[1]), fminf(wred[2], wred[3]));
    mx = fmaxf(fmaxf(wred[4], wred[5]), fmaxf(wred[6], wred[7]));

    for (int r = 0; r < 16; ++r) {
        const int i = rg * 64 + wv * 16 + r;
        const float xi = xs[i];
        const float li = (xi >= 0.f) ? xi * mn : xi * mx;
        const float nxi = -xi;
        float sum = 0.f, d1 = 0.f, d2 = 0.f;
        #pragma unroll
        for (int g = 0; g < 8; ++g) {
            const int o = g * 256 + lane * 4;
            f32x4 xv = *reinterpret_cast<const f32x4*>(&xs[o]);
            f32x4 v1 = *reinterpret_cast<const f32x4*>(&xs1[o]);
            f32x4 v2 = *reinterpret_cast<const f32x4*>(&xs2[o]);
            #pragma unroll
            for (int c = 0; c < 4; ++c) {
                float ev = __expf(fmaf(nxi, xv[c], li));
                sum += ev;
                d1 = fmaf(ev, v1[c], d1);
                d2 = fmaf(ev, v2[c], d2);
            }
        }
        #pragma unroll
        for (int off = 32; off > 0; off >>= 1) {
            sum += __shfl_xor(sum, off);
            d1  += __shfl_xor(d1, off);
            d2  += __shfl_xor(d2, off);
        }
        const float inv = 1.f / sum;
        if (lane == 0) {
            out1[b * CDIM + i] = fmaf(d1, inv, xs1[i]);
            out2[b * CDIM + i] = fmaf(d2, inv, xs2[i]);
        }
        float* arow = att + (size_t)(b * CDIM + i) * CDIM;
        #pragma unroll
        for (int g = 0; g < 8; ++g) {
            const int o = g * 256 + lane * 4;
            f32x4 xv = *reinterpret_cast<const f32x4*>(&xs[o]);
            f32x4 v;
            #pragma unroll
            for (int c = 0; c < 4; ++c)
                v[c] = __expf(fmaf(nxi, xv[c], li)) * inv;
            *reinterpret_cast<f32x4*>(arow + o) = v;
        }
    }
}

extern "C" void kernel_launch(void* const* d_in, const int* in_sizes, int n_in,
                              void* d_out, int out_size, void* d_ws, size_t ws_size,
                              hipStream_t stream) {
    const float* x1   = (const float*)d_in[0];
    const float* x2   = (const float*)d_in[1];
    const float* W    = (const float*)d_in[2];
    const float* bias = (const float*)d_in[3];
    float* out  = (float*)d_out;
    float* out1 = out;
    float* out2 = out + BATCH * CDIM;
    float* att  = out + 2 * BATCH * CDIM;

    float* xrow = (float*)d_ws;                 // 256 KB
    float* liS  = xrow + BATCH * CDIM;          // 256 KB
    float* invS = liS  + BATCH * CDIM;          // 256 KB

    // GEMM partials live in the tail of the attention region; fully consumed
    // by reduce_x_k before the attention phase overwrites that region.
    float* partial = out + ((size_t)out_size - (size_t)KT * BATCH * CDIM);

    gemm_partial_k<<<dim3(NT, KT), dim3(256), 0, stream>>>(x1, x2, W, partial);
    reduce_x_k<<<(BATCH * CDIM) / 256, 256, 0, stream>>>(partial, bias, xrow);

    if (ws_size >= (size_t)3 * BATCH * CDIM * sizeof(float)) {
        attn_sums_k<<<BATCH * (CDIM / 64), 256, 0, stream>>>(
            xrow, x1, x2, out1, out2, liS, invS);
        attn_store_k<<<BATCH * (CDIM / 64), 256, 0, stream>>>(
            xrow, liS, invS, att);
    } else {
        attn_k<<<BATCH * (CDIM / 64), 256, 0, stream>>>(
            xrow, x1, x2, out1, out2, att);
    }
}

// Round 12
// 124.973 us; speedup vs baseline: 1.9547x; 1.2619x over previous
//
#include <hip/hip_runtime.h>

#define CDIM 2048
#define BATCH 32
#define K2 4096
#define BN 64
#define BK 128
#define KT (K2 / BK)    // 32
#define NT (CDIM / BN)  // 32

typedef float f32x4 __attribute__((ext_vector_type(4)));

// ---- GEMM partial (R7): partial[kt] = xcat[:, k0:k0+BK] @ W[:, k0:k0+BK]^T ----
__global__ __launch_bounds__(256) void gemm_partial_k(
    const float* __restrict__ x1, const float* __restrict__ x2,
    const float* __restrict__ W, float* __restrict__ partial)
{
    __shared__ float lds[BN * BK + BATCH * BK];
    float* Wt = lds;
    float* Xs = lds + BN * BK;

    const int nt = blockIdx.x, kt = blockIdx.y;
    const int i0 = nt * BN, k0 = kt * BK;
    const int t = threadIdx.x;
    const int lane = t & 63, ks = t >> 6;
    const int cg8 = lane & 7, bg = lane >> 3;

    const float* xsrc = (k0 < CDIM) ? x1 : x2;
    const int kk0 = k0 & (CDIM - 1);

    #pragma unroll
    for (int r = 0; r < 8; ++r) {
        int f = t + 256 * r;
        int row = f >> 5, kc = f & 31;
        float4 v = *reinterpret_cast<const float4*>(W + (size_t)(i0 + row) * K2 + k0 + kc * 4);
        int sc = kc ^ ((row >> 3) & 7);
        *reinterpret_cast<float4*>(&Wt[row * BK + sc * 4]) = v;
    }
    #pragma unroll
    for (int r = 0; r < 4; ++r) {
        int f = t + 256 * r;
        int row = f >> 5, kc = f & 31;
        float4 v = *reinterpret_cast<const float4*>(xsrc + row * CDIM + kk0 + kc * 4);
        int sc = kc ^ ((row >> 2) & 7);
        *reinterpret_cast<float4*>(&Xs[row * BK + sc * 4]) = v;
    }
    __syncthreads();

    float acc[4][8] = {};
    #pragma unroll 2
    for (int s = 0; s < 8; ++s) {
        const int kc = ks * 8 + s;
        f32x4 xv[4], wv[8];
        #pragma unroll
        for (int bb = 0; bb < 4; ++bb)
            xv[bb] = *reinterpret_cast<const f32x4*>(&Xs[(4 * bg + bb) * BK + (kc ^ bg) * 4]);
        #pragma unroll
        for (int cc = 0; cc < 8; ++cc)
            wv[cc] = *reinterpret_cast<const f32x4*>(&Wt[(8 * cg8 + cc) * BK + (kc ^ cg8) * 4]);
        #pragma unroll
        for (int bb = 0; bb < 4; ++bb)
            #pragma unroll
            for (int cc = 0; cc < 8; ++cc)
                #pragma unroll
                for (int w = 0; w < 4; ++w)
                    acc[bb][cc] = fmaf(xv[bb][w], wv[cc][w], acc[bb][cc]);
    }

    __syncthreads();
    float* accS = lds;
    #pragma unroll
    for (int bb = 0; bb < 4; ++bb)
        #pragma unroll
        for (int cc = 0; cc < 8; ++cc)
            accS[(ks * 64 + lane) * 33 + bb * 8 + cc] = acc[bb][cc];
    __syncthreads();

    {
        const int l0 = t >> 2, q = t & 3;
        float s0[8];
        #pragma unroll
        for (int j = 0; j < 8; ++j) {
            float s = 0.f;
            #pragma unroll
            for (int k = 0; k < 4; ++k)
                s += accS[(k * 64 + l0) * 33 + q * 8 + j];
            s0[j] = s;
        }
        const int b_row = 4 * (l0 >> 3) + q;
        const int icol  = 8 * (l0 & 7);
        float* dst = partial + (size_t)kt * (BATCH * CDIM) + b_row * CDIM + i0 + icol;
        *reinterpret_cast<float4*>(dst)     = make_float4(s0[0], s0[1], s0[2], s0[3]);
        *reinterpret_cast<float4*>(dst + 4) = make_float4(s0[4], s0[5], s0[6], s0[7]);
    }
}

__global__ __launch_bounds__(256) void reduce_x_k(
    const float* __restrict__ partial, const float* __restrict__ bias,
    float* __restrict__ x)
{
    int idx = blockIdx.x * 256 + threadIdx.x;
    float s = 0.f;
    #pragma unroll
    for (int kt = 0; kt < KT; ++kt) s += partial[(size_t)kt * (BATCH * CDIM) + idx];
    x[idx] = s + bias[idx & (CDIM - 1)];
}

// ---- Attention with one-row software pipeline: stores of row i interleave
// with sum-accumulation of row i+1 in the SAME g-loop, so the store stream
// never pauses (convoy-breaking). Bit-identical values/order vs R7. ----
__global__ __launch_bounds__(256) void attn_k(
    const float* __restrict__ x, const float* __restrict__ x1,
    const float* __restrict__ x2, float* __restrict__ out1,
    float* __restrict__ out2, float* __restrict__ att)
{
    __shared__ float xs[CDIM];
    __shared__ float xs1[CDIM];
    __shared__ float xs2[CDIM];
    __shared__ float wred[8];
    const int b = blockIdx.x >> 5, rg = blockIdx.x & 31;
    const int t = threadIdx.x;
    const int lane = t & 63, wv = t >> 6;
    const float* xb  = x  + b * CDIM;
    const float* x1b = x1 + b * CDIM;
    const float* x2b = x2 + b * CDIM;

    #pragma unroll
    for (int r = 0; r < 2; ++r) {
        int f = (t + 256 * r) * 4;
        *reinterpret_cast<float4*>(&xs[f])  = *reinterpret_cast<const float4*>(xb  + f);
        *reinterpret_cast<float4*>(&xs1[f]) = *reinterpret_cast<const float4*>(x1b + f);
        *reinterpret_cast<float4*>(&xs2[f]) = *reinterpret_cast<const float4*>(x2b + f);
    }
    __syncthreads();

    // block min/max of x[b,:]
    float mn = 1e30f, mx = -1e30f;
    for (int f = t; f < CDIM; f += 256) {
        float v = xs[f];
        mn = fminf(mn, v); mx = fmaxf(mx, v);
    }
    #pragma unroll
    for (int off = 32; off > 0; off >>= 1) {
        mn = fminf(mn, __shfl_xor(mn, off));
        mx = fmaxf(mx, __shfl_xor(mx, off));
    }
    if (lane == 0) { wred[wv] = mn; wred[4 + wv] = mx; }
    __syncthreads();
    mn = fminf(fminf(wred[0], wred[1]), fminf(wred[2], wred[3]));
    mx = fmaxf(fmaxf(wred[4], wred[5]), fmaxf(wred[6], wred[7]));

    const int base = rg * 64 + wv * 16;

    // ---- prologue: sums for row `base` ----
    float li_c, inv_c, nxi_c;
    {
        const int i = base;
        const float xi = xs[i];
        li_c  = (xi >= 0.f) ? xi * mn : xi * mx; // min_j(x_i*x_j), exact
        nxi_c = -xi;
        float sum = 0.f, d1 = 0.f, d2 = 0.f;
        #pragma unroll
        for (int g = 0; g < 8; ++g) {
            const int o = g * 256 + lane * 4;
            f32x4 xv = *reinterpret_cast<const f32x4*>(&xs[o]);
            f32x4 v1 = *reinterpret_cast<const f32x4*>(&xs1[o]);
            f32x4 v2 = *reinterpret_cast<const f32x4*>(&xs2[o]);
            #pragma unroll
            for (int c = 0; c < 4; ++c) {
                float ev = __expf(fmaf(nxi_c, xv[c], li_c));
                sum += ev;
                d1 = fmaf(ev, v1[c], d1);
                d2 = fmaf(ev, v2[c], d2);
            }
        }
        #pragma unroll
        for (int off = 32; off > 0; off >>= 1) {
            sum += __shfl_xor(sum, off);
            d1  += __shfl_xor(d1, off);
            d2  += __shfl_xor(d2, off);
        }
        inv_c = 1.f / sum;
        if (lane == 0) {
            out1[b * CDIM + i] = fmaf(d1, inv_c, xs1[i]);
            out2[b * CDIM + i] = fmaf(d2, inv_c, xs2[i]);
        }
    }

    // ---- main: store row i while accumulating sums for row i+1 ----
    for (int r = 0; r < 15; ++r) {
        const int i  = base + r;
        const int i1 = i + 1;
        const float xi1 = xs[i1];
        const float li1 = (xi1 >= 0.f) ? xi1 * mn : xi1 * mx;
        const float nxi1 = -xi1;
        float sum = 0.f, d1 = 0.f, d2 = 0.f;
        float* arow = att + (size_t)(b * CDIM + i) * CDIM;
        #pragma unroll
        for (int g = 0; g < 8; ++g) {
            const int o = g * 256 + lane * 4;
            f32x4 xv = *reinterpret_cast<const f32x4*>(&xs[o]);
            f32x4 v1 = *reinterpret_cast<const f32x4*>(&xs1[o]);
            f32x4 v2 = *reinterpret_cast<const f32x4*>(&xs2[o]);
            f32x4 v;
            #pragma unroll
            for (int c = 0; c < 4; ++c)
                v[c] = __expf(fmaf(nxi_c, xv[c], li_c)) * inv_c;
            *reinterpret_cast<f32x4*>(arow + o) = v;
            #pragma unroll
            for (int c = 0; c < 4; ++c) {
                float ev = __expf(fmaf(nxi1, xv[c], li1));
                sum += ev;
                d1 = fmaf(ev, v1[c], d1);
                d2 = fmaf(ev, v2[c], d2);
            }
        }
        #pragma unroll
        for (int off = 32; off > 0; off >>= 1) {
            sum += __shfl_xor(sum, off);
            d1  += __shfl_xor(d1, off);
            d2  += __shfl_xor(d2, off);
        }
        const float inv1 = 1.f / sum;
        if (lane == 0) {
            out1[b * CDIM + i1] = fmaf(d1, inv1, xs1[i1]);
            out2[b * CDIM + i1] = fmaf(d2, inv1, xs2[i1]);
        }
        li_c = li1; nxi_c = nxi1; inv_c = inv1;
    }

    // ---- epilogue: store last row ----
    {
        const int i = base + 15;
        float* arow = att + (size_t)(b * CDIM + i) * CDIM;
        #pragma unroll
        for (int g = 0; g < 8; ++g) {
            const int o = g * 256 + lane * 4;
            f32x4 xv = *reinterpret_cast<const f32x4*>(&xs[o]);
            f32x4 v;
            #pragma unroll
            for (int c = 0; c < 4; ++c)
                v[c] = __expf(fmaf(nxi_c, xv[c], li_c)) * inv_c;
            *reinterpret_cast<f32x4*>(arow + o) = v;
        }
    }
}

extern "C" void kernel_launch(void* const* d_in, const int* in_sizes, int n_in,
                              void* d_out, int out_size, void* d_ws, size_t ws_size,
                              hipStream_t stream) {
    const float* x1   = (const float*)d_in[0];
    const float* x2   = (const float*)d_in[1];
    const float* W    = (const float*)d_in[2];
    const float* bias = (const float*)d_in[3];
    float* out  = (float*)d_out;
    float* out1 = out;
    float* out2 = out + BATCH * CDIM;
    float* att  = out + 2 * BATCH * CDIM;
    float* xrow = (float*)d_ws;

    // GEMM partials live in the tail of the attention region; fully consumed
    // by reduce_x_k before attn_k overwrites that region.
    float* partial = out + ((size_t)out_size - (size_t)KT * BATCH * CDIM);

    gemm_partial_k<<<dim3(NT, KT), dim3(256), 0, stream>>>(x1, x2, W, partial);
    reduce_x_k<<<(BATCH * CDIM) / 256, 256, 0, stream>>>(partial, bias, xrow);
    attn_k<<<BATCH * (CDIM / 64), 256, 0, stream>>>(xrow, x1, x2, out1, out2, att);
}